// Round 11
// baseline (106.101 us; speedup 1.0000x reference)
//
#include <hip/hip_runtime.h>
#include <math.h>

#define B_    2
#define LQ_   12240
#define C_    256
#define NH_   8
#define NL_   4
#define NP_   4
#define LEN_IN_ 12240
#define MROWS (B_*LQ_)    // 24480
#define MF_   (MROWS/16)  // 1530
#define KF_   8           // 256/32
#define APLANE ((size_t)MROWS * C_)
#define NBLK  383          // ceil(MROWS/64)
#define GRIDX 128          // persistent blocks per matrix

typedef __attribute__((ext_vector_type(8))) short short8v;
typedef __attribute__((ext_vector_type(4))) float f32x4;
typedef __attribute__((ext_vector_type(2))) float f32x2;
typedef __attribute__((ext_vector_type(2))) uint  u32x2;

__device__ __forceinline__ ushort f2bf_hi(float f) {
    uint u = __builtin_bit_cast(uint, f);
    uint r = (u + 0x7fffu + ((u >> 16) & 1u)) >> 16;
    return (ushort)r;
}
__device__ __forceinline__ float bf2f(ushort h) {
    uint u = ((uint)h) << 16;
    return __builtin_bit_cast(float, u);
}

// packed-B layout (uint4 units):
#define U4_VAL  0
#define U4_OFF  8192
#define U4_ATT  16384
#define U4_UHI  20480
#define U4_ULO  28672
#define PACKB_TOTAL 294912   // ushorts

// ---------------------------------------------------------------------------
// Weights-only pack: B-fragment order, hi (+lo for W_out).
// ---------------------------------------------------------------------------
__global__ __launch_bounds__(256) void pack_w_kernel(
    const float* __restrict__ Wv, const float* __restrict__ Wo,
    const float* __restrict__ Wa, const float* __restrict__ Wu,
    ushort* __restrict__ packB)
{
    int gid = blockIdx.x * 256 + threadIdx.x;
    if (gid >= 28672) return;
    const float* W; ushort* hi; ushort* lo = nullptr; int N, rel;
    if (gid < 8192)       { W = Wv; hi = packB;          N = 256; rel = gid; }
    else if (gid < 16384) { W = Wo; hi = packB + 65536;  N = 256; rel = gid - 8192; }
    else if (gid < 20480) { W = Wa; hi = packB + 131072; N = 128; rel = gid - 16384; }
    else { W = Wu; hi = packB + 163840; lo = packB + 229376; N = 256; rel = gid - 20480; }

    const int lane = rel & 63;
    const int kf   = (rel >> 6) & 7;
    const int nf   = rel >> 9;
    const int row0 = kf * 32 + (lane >> 4) * 8;
    const int col  = nf * 16 + (lane & 15);

    union { ushort u16[8]; uint4 u4; } ch, cl;
#pragma unroll
    for (int j = 0; j < 8; ++j) {
        float x = W[(size_t)(row0 + j) * N + col];
        ushort h = f2bf_hi(x);
        ch.u16[j] = h;
        cl.u16[j] = f2bf_hi(x - bf2f(h));
    }
    *reinterpret_cast<uint4*>(hi + (size_t)rel * 8) = ch.u4;
    if (lo) *reinterpret_cast<uint4*>(lo + (size_t)rel * 8) = cl.u4;
}

// ---------------------------------------------------------------------------
// Merged value+query GEMM, persistent blocks + double-buffered A staging.
// grid (GRIDX, 2): y==0 value, y==1 offs+attn(+softmax).  Each block walks
// tiles {bx, bx+128, bx+256}; per tile: issue next-tile global loads, compute
// current from LDS, convert+write next into other buffer, one barrier.
// ---------------------------------------------------------------------------
__global__ __launch_bounds__(512) void gemm_vq_kernel(
    const float* __restrict__ inflat, const float* __restrict__ query,
    const ushort* __restrict__ packB,
    const float* __restrict__ b_val, const float* __restrict__ b_off,
    const float* __restrict__ b_attn,
    ushort* __restrict__ valbf, float* __restrict__ offsb, float* __restrict__ attnb)
{
    const int t = threadIdx.x, lane = t & 63, wid = t >> 6;
    const bool isVal = (blockIdx.y == 0);
    const float* __restrict__ A = isVal ? inflat : query;

    __shared__ ushort Als[2][2048 * 8];   // 2 x 32 KB

    int sfrag[4], srow[4], sk0[4];
#pragma unroll
    for (int i = 0; i < 4; ++i) {
        int frag = i * 512 + t;
        sfrag[i] = frag;
        int fl = frag & 63;
        srow[i] = (frag >> 9) * 16 + (fl & 15);
        sk0[i]  = ((frag >> 6) & 7) * 32 + (fl >> 4) * 8;
    }

    const int colLane = lane & 15, rquad = lane >> 4;
    const int wnf = wid * 2;

    float4 ld[4][2];
    // prologue: load + write first tile into buf 0
#pragma unroll
    for (int i = 0; i < 4; ++i) {
        int row = min(blockIdx.x * 64 + srow[i], MROWS - 1);
        const float4* s = reinterpret_cast<const float4*>(A + (size_t)row * 256 + sk0[i]);
        ld[i][0] = s[0]; ld[i][1] = s[1];
    }
#pragma unroll
    for (int i = 0; i < 4; ++i) {
        float vv[8] = { ld[i][0].x, ld[i][0].y, ld[i][0].z, ld[i][0].w,
                        ld[i][1].x, ld[i][1].y, ld[i][1].z, ld[i][1].w };
        union { ushort u16[8]; uint4 u4; } hh;
#pragma unroll
        for (int j = 0; j < 8; ++j) hh.u16[j] = f2bf_hi(vv[j]);
        *reinterpret_cast<uint4*>(&Als[0][(size_t)sfrag[i] * 8]) = hh.u4;
    }
    __syncthreads();

    int buf = 0;
    for (int tile = blockIdx.x; tile < NBLK; tile += GRIDX) {
        const int rowBase = tile * 64;
        const bool hasNext = (tile + GRIDX) < NBLK;

        // issue next tile's global loads (latency hides under compute)
        if (hasNext) {
            int nrb = (tile + GRIDX) * 64;
#pragma unroll
            for (int i = 0; i < 4; ++i) {
                int row = min(nrb + srow[i], MROWS - 1);
                const float4* s = reinterpret_cast<const float4*>(A + (size_t)row * 256 + sk0[i]);
                ld[i][0] = s[0]; ld[i][1] = s[1];
            }
        }

        const uint4* A4 = reinterpret_cast<const uint4*>(Als[buf]);

        if (isVal) {
            const uint4* B4 = reinterpret_cast<const uint4*>(packB) + U4_VAL;
            f32x4 acc[4][2];
#pragma unroll
            for (int mi = 0; mi < 4; ++mi)
#pragma unroll
                for (int f = 0; f < 2; ++f) acc[mi][f] = (f32x4)0.0f;

#pragma unroll
            for (int kf = 0; kf < KF_; ++kf) {
                uint4 bh[2], ah[4];
#pragma unroll
                for (int f = 0; f < 2; ++f) bh[f] = B4[((wnf + f) * KF_ + kf) * 64 + lane];
#pragma unroll
                for (int mi = 0; mi < 4; ++mi) ah[mi] = A4[(mi * KF_ + kf) * 64 + lane];
#pragma unroll
                for (int mi = 0; mi < 4; ++mi) {
                    short8v a = __builtin_bit_cast(short8v, ah[mi]);
#pragma unroll
                    for (int f = 0; f < 2; ++f)
                        acc[mi][f] = __builtin_amdgcn_mfma_f32_16x16x32_bf16(
                            a, __builtin_bit_cast(short8v, bh[f]), acc[mi][f], 0, 0, 0);
                }
            }
#pragma unroll
            for (int f = 0; f < 2; ++f) {
                int col = (wnf + f) * 16 + colLane;
                float bv = b_val[col];
#pragma unroll
                for (int mi = 0; mi < 4; ++mi)
#pragma unroll
                    for (int e = 0; e < 4; ++e) {
                        int row = rowBase + mi * 16 + rquad * 4 + e;
                        if (row < MROWS) valbf[(size_t)row * 256 + col] = f2bf_hi(acc[mi][f][e] + bv);
                    }
            }
        } else {
            const uint4* BO = reinterpret_cast<const uint4*>(packB) + U4_OFF;
            const uint4* BA = reinterpret_cast<const uint4*>(packB) + U4_ATT;
            f32x4 acc[4][3];
#pragma unroll
            for (int mi = 0; mi < 4; ++mi)
#pragma unroll
                for (int f = 0; f < 3; ++f) acc[mi][f] = (f32x4)0.0f;

#pragma unroll
            for (int kf = 0; kf < KF_; ++kf) {
                uint4 bh[3], ah[4];
#pragma unroll
                for (int f = 0; f < 2; ++f) bh[f] = BO[((wnf + f) * KF_ + kf) * 64 + lane];
                bh[2] = BA[(wid * KF_ + kf) * 64 + lane];
#pragma unroll
                for (int mi = 0; mi < 4; ++mi) ah[mi] = A4[(mi * KF_ + kf) * 64 + lane];
#pragma unroll
                for (int mi = 0; mi < 4; ++mi) {
                    short8v a = __builtin_bit_cast(short8v, ah[mi]);
#pragma unroll
                    for (int f = 0; f < 3; ++f)
                        acc[mi][f] = __builtin_amdgcn_mfma_f32_16x16x32_bf16(
                            a, __builtin_bit_cast(short8v, bh[f]), acc[mi][f], 0, 0, 0);
                }
            }
#pragma unroll
            for (int f = 0; f < 2; ++f) {
                int col = (wnf + f) * 16 + colLane;
                float bv = b_off[col];
#pragma unroll
                for (int mi = 0; mi < 4; ++mi)
#pragma unroll
                    for (int e = 0; e < 4; ++e) {
                        int row = rowBase + mi * 16 + rquad * 4 + e;
                        if (row < MROWS) offsb[(size_t)row * 256 + col] = acc[mi][f][e] + bv;
                    }
            }
            {
                int col = wid * 16 + colLane;
                float bv = b_attn[col];
#pragma unroll
                for (int mi = 0; mi < 4; ++mi)
#pragma unroll
                    for (int e = 0; e < 4; ++e) {
                        float v = acc[mi][2][e] + bv;
                        float mx = v;
#pragma unroll
                        for (int m = 8; m >= 1; m >>= 1) mx = fmaxf(mx, __shfl_xor(mx, m, 16));
                        float ex = __expf(v - mx);
                        float s = ex;
#pragma unroll
                        for (int m = 8; m >= 1; m >>= 1) s += __shfl_xor(s, m, 16);
                        int row = rowBase + mi * 16 + rquad * 4 + e;
                        if (row < MROWS) attnb[(size_t)row * 128 + col] = ex / s;
                    }
            }
        }

        // convert + write next tile into the other buffer
        if (hasNext) {
#pragma unroll
            for (int i = 0; i < 4; ++i) {
                float vv[8] = { ld[i][0].x, ld[i][0].y, ld[i][0].z, ld[i][0].w,
                                ld[i][1].x, ld[i][1].y, ld[i][1].z, ld[i][1].w };
                union { ushort u16[8]; uint4 u4; } hh;
#pragma unroll
                for (int j = 0; j < 8; ++j) hh.u16[j] = f2bf_hi(vv[j]);
                *reinterpret_cast<uint4*>(&Als[buf ^ 1][(size_t)sfrag[i] * 8]) = hh.u4;
            }
        }
        __syncthreads();
        buf ^= 1;
    }
}

// ---------------------------------------------------------------------------
// Out GEMM: out(f32) = midH(bf16) @ (Wu_hi + Wu_lo) + b_out.
// Same persistent + double-buffered staging structure (lighter: uint4 copy).
// ---------------------------------------------------------------------------
__global__ __launch_bounds__(512) void gemm_out_kernel(
    const ushort* __restrict__ midH, const ushort* __restrict__ packB,
    const float* __restrict__ bias, float* __restrict__ Cg)
{
    const int t = threadIdx.x, lane = t & 63, wid = t >> 6;

    __shared__ ushort Ahs[2][2048 * 8];

    int sfrag[4], srow[4], skq[4];
#pragma unroll
    for (int i = 0; i < 4; ++i) {
        int frag = i * 512 + t;
        sfrag[i] = frag;
        int fl = frag & 63;
        srow[i] = (frag >> 9) * 16 + (fl & 15);
        skq[i]  = ((frag >> 6) & 7) * 4 + (fl >> 4);
    }

    const uint4* H4 = reinterpret_cast<const uint4*>(midH);
    const int colLane = lane & 15, rquad = lane >> 4;
    const int wnf = wid * 2;

    uint4 ld[4];
#pragma unroll
    for (int i = 0; i < 4; ++i) {
        int row = min(blockIdx.x * 64 + srow[i], MROWS - 1);
        ld[i] = H4[(size_t)row * 32 + skq[i]];
    }
#pragma unroll
    for (int i = 0; i < 4; ++i)
        *reinterpret_cast<uint4*>(&Ahs[0][(size_t)sfrag[i] * 8]) = ld[i];
    __syncthreads();

    const uint4* BH4 = reinterpret_cast<const uint4*>(packB) + U4_UHI;
    const uint4* BL4 = reinterpret_cast<const uint4*>(packB) + U4_ULO;

    int buf = 0;
    for (int tile = blockIdx.x; tile < NBLK; tile += GRIDX) {
        const int rowBase = tile * 64;
        const bool hasNext = (tile + GRIDX) < NBLK;

        if (hasNext) {
            int nrb = (tile + GRIDX) * 64;
#pragma unroll
            for (int i = 0; i < 4; ++i) {
                int row = min(nrb + srow[i], MROWS - 1);
                ld[i] = H4[(size_t)row * 32 + skq[i]];
            }
        }

        const uint4* A4 = reinterpret_cast<const uint4*>(Ahs[buf]);

        f32x4 acc[4][2];
#pragma unroll
        for (int mi = 0; mi < 4; ++mi)
#pragma unroll
            for (int f = 0; f < 2; ++f) acc[mi][f] = (f32x4)0.0f;

#pragma unroll
        for (int kf = 0; kf < KF_; ++kf) {
            uint4 bh[2], bl[2], ah[4];
#pragma unroll
            for (int f = 0; f < 2; ++f) {
                bh[f] = BH4[((wnf + f) * KF_ + kf) * 64 + lane];
                bl[f] = BL4[((wnf + f) * KF_ + kf) * 64 + lane];
            }
#pragma unroll
            for (int mi = 0; mi < 4; ++mi) ah[mi] = A4[(mi * KF_ + kf) * 64 + lane];
#pragma unroll
            for (int mi = 0; mi < 4; ++mi) {
                short8v a = __builtin_bit_cast(short8v, ah[mi]);
#pragma unroll
                for (int f = 0; f < 2; ++f) {
                    acc[mi][f] = __builtin_amdgcn_mfma_f32_16x16x32_bf16(
                        a, __builtin_bit_cast(short8v, bh[f]), acc[mi][f], 0, 0, 0);
                    acc[mi][f] = __builtin_amdgcn_mfma_f32_16x16x32_bf16(
                        a, __builtin_bit_cast(short8v, bl[f]), acc[mi][f], 0, 0, 0);
                }
            }
        }

#pragma unroll
        for (int f = 0; f < 2; ++f) {
            int col = (wnf + f) * 16 + colLane;
            float bv = bias[col];
#pragma unroll
            for (int mi = 0; mi < 4; ++mi)
#pragma unroll
                for (int e = 0; e < 4; ++e) {
                    int row = rowBase + mi * 16 + rquad * 4 + e;
                    if (row < MROWS) Cg[(size_t)row * 256 + col] = acc[mi][f][e] + bv;
                }
        }

        if (hasNext) {
#pragma unroll
            for (int i = 0; i < 4; ++i)
                *reinterpret_cast<uint4*>(&Ahs[buf ^ 1][(size_t)sfrag[i] * 8]) = ld[i];
        }
        __syncthreads();
        buf ^= 1;
    }
}

// ---------------------------------------------------------------------------
// Sampler: softmax pre-applied; packed f32 FMA + free-hi bf16 decode.
// ---------------------------------------------------------------------------
__global__ __launch_bounds__(128) void sampler_kernel(
    const ushort* __restrict__ value,
    const float* __restrict__ offs,
    const float* __restrict__ attnw,   // softmaxed weights
    const float* __restrict__ refp,
    ushort* __restrict__ midH)
{
    const int t  = threadIdx.x;
    const int qi = t >> 6;
    const int t6 = t & 63;
    const int q  = blockIdx.x * 2 + qi;

    __shared__ float s_ref[2][8];
    __shared__ int   s_addr[2][576];
    __shared__ float s_w[2][576];

    if (t < 16) s_ref[t >> 3][t & 7] = refp[(size_t)(blockIdx.x * 2 + (t >> 3)) * 8 + (t & 7)];
    __syncthreads();

#pragma unroll
    for (int batch = 0; batch < 2; ++batch) {
        const int p  = t6 + batch * 64;
        const int h  = p >> 4;
        const int lp = p & 15;
        const int l  = lp >> 2;

        const float aw = attnw[(size_t)q * 128 + p];
        const float2 o = reinterpret_cast<const float2*>(offs)[(size_t)q * 128 + p];
        const float rx = s_ref[qi][l * 2 + 0];
        const float ry = s_ref[qi][l * 2 + 1];

        const int   Wl = 96 >> l;
        const int   st = 12288 - (12288 >> (2 * l));
        const float fW = (float)Wl;

        const float x = fmaf(rx, fW, o.x) - 0.5f;
        const float y = fmaf(ry, fW, o.y) - 0.5f;
        const float x0f = floorf(x), y0f = floorf(y);
        const float fx = x - x0f, fy = y - y0f;
        const int x0 = (int)x0f, y0 = (int)y0f;
        const int x1 = x0 + 1,   y1 = y0 + 1;

        const float vx0 = (x0 >= 0 && x0 < Wl) ? 1.f : 0.f;
        const float vx1 = (x1 >= 0 && x1 < Wl) ? 1.f : 0.f;
        const float vy0 = (y0 >= 0 && y0 < Wl) ? 1.f : 0.f;
        const float vy1 = (y1 >= 0 && y1 < Wl) ? 1.f : 0.f;

        const int xc0 = min(max(x0, 0), Wl - 1);
        const int xc1 = min(max(x1, 0), Wl - 1);
        const int yc0 = min(max(y0, 0), Wl - 1);
        const int yc1 = min(max(y1, 0), Wl - 1);

        const int row0 = st + yc0 * Wl;
        const int row1 = st + yc1 * Wl;
        const int hb   = h << 5;

        const int sidx = (lp * 9 + h) * 4;
        int4 a;
        a.x = ((row0 + xc0) << 8) + hb;
        a.y = ((row0 + xc1) << 8) + hb;
        a.z = ((row1 + xc0) << 8) + hb;
        a.w = ((row1 + xc1) << 8) + hb;
        *reinterpret_cast<int4*>(&s_addr[qi][sidx]) = a;

        float4 w;
        w.x = aw * (1.f - fx) * (1.f - fy) * vx0 * vy0;
        w.y = aw * fx * (1.f - fy) * vx1 * vy0;
        w.z = aw * (1.f - fx) * fy * vx0 * vy1;
        w.w = aw * fx * fy * vx1 * vy1;
        *reinterpret_cast<float4*>(&s_w[qi][sidx]) = w;
    }
    __syncthreads();

    const int c2 = t6 >> 5;
    const int h  = (t6 >> 2) & 7;
    const int l2 = t6 & 3;
    const int d8 = l2 * 8;
    const ushort* __restrict__ vb = value + (q >= LQ_ ? (size_t)LEN_IN_ * 256 : 0) + d8;

    f32x2 aLo = (f32x2)0.f, aHi = (f32x2)0.f, bLo = (f32x2)0.f, bHi = (f32x2)0.f;

#pragma unroll
    for (int pt = 0; pt < 16; ++pt) {
        const int base = (pt * 9 + h) * 4 + c2 * 2;
        const int2   a = *reinterpret_cast<const int2*>(&s_addr[qi][base]);
        const float2 w = *reinterpret_cast<const float2*>(&s_w[qi][base]);
        uint4 v0 = *reinterpret_cast<const uint4*>(vb + a.x);
        uint4 v1 = *reinterpret_cast<const uint4*>(vb + a.y);
        f32x2 w0; w0.x = w.x; w0.y = w.x;
        f32x2 w1; w1.x = w.y; w1.y = w.y;

        u32x2 h01; h01.x = v0.x; h01.y = v0.y;
        u32x2 h23; h23.x = v0.z; h23.y = v0.w;
        u32x2 l01 = h01 << 16, l23 = h23 << 16;
        aHi = __builtin_elementwise_fma(__builtin_bit_cast(f32x2, h01), w0, aHi);
        aLo = __builtin_elementwise_fma(__builtin_bit_cast(f32x2, l01), w0, aLo);
        bHi = __builtin_elementwise_fma(__builtin_bit_cast(f32x2, h23), w0, bHi);
        bLo = __builtin_elementwise_fma(__builtin_bit_cast(f32x2, l23), w0, bLo);

        u32x2 g01; g01.x = v1.x; g01.y = v1.y;
        u32x2 g23; g23.x = v1.z; g23.y = v1.w;
        u32x2 m01 = g01 << 16, m23 = g23 << 16;
        aHi = __builtin_elementwise_fma(__builtin_bit_cast(f32x2, g01), w1, aHi);
        aLo = __builtin_elementwise_fma(__builtin_bit_cast(f32x2, m01), w1, aLo);
        bHi = __builtin_elementwise_fma(__builtin_bit_cast(f32x2, g23), w1, bHi);
        bLo = __builtin_elementwise_fma(__builtin_bit_cast(f32x2, m23), w1, bLo);
    }

    float r[8] = { aLo.x, aHi.x, aLo.y, aHi.y, bLo.x, bHi.x, bLo.y, bHi.y };
#pragma unroll
    for (int j = 0; j < 8; ++j) r[j] += __shfl_xor(r[j], 32);

    if (c2 == 0) {
        union { ushort u16[8]; uint4 u4; } hh;
#pragma unroll
        for (int j = 0; j < 8; ++j) hh.u16[j] = f2bf_hi(r[j]);
        *reinterpret_cast<uint4*>(midH + (size_t)q * 256 + (h << 5) + d8) = hh.u4;
    }
}

// ---------------------------------------------------------------------------
extern "C" void kernel_launch(void* const* d_in, const int* in_sizes, int n_in,
                              void* d_out, int out_size, void* d_ws, size_t ws_size,
                              hipStream_t stream)
{
    const float* query  = (const float*)d_in[0];
    const float* refp   = (const float*)d_in[1];
    const float* inflat = (const float*)d_in[2];
    const float* W_off  = (const float*)d_in[5];
    const float* b_off  = (const float*)d_in[6];
    const float* W_attn = (const float*)d_in[7];
    const float* b_attn = (const float*)d_in[8];
    const float* W_val  = (const float*)d_in[9];
    const float* b_val  = (const float*)d_in[10];
    const float* W_out  = (const float*)d_in[11];
    const float* b_out  = (const float*)d_in[12];
    float* out = (float*)d_out;

    ushort* midH  = (ushort*)d_ws;
    ushort* valbf = midH + APLANE;
    ushort* packB = valbf + APLANE;
    float*  offsb = (float*)(packB + PACKB_TOTAL);
    float*  attnb = offsb + APLANE;

    hipLaunchKernelGGL(pack_w_kernel, dim3(112), dim3(256), 0, stream,
                       W_val, W_off, W_attn, W_out, packB);
    hipLaunchKernelGGL(gemm_vq_kernel, dim3(GRIDX, 2), dim3(512), 0, stream,
                       inflat, query, packB, b_val, b_off, b_attn,
                       valbf, offsb, attnb);
    hipLaunchKernelGGL(sampler_kernel, dim3(MROWS / 2), dim3(128), 0, stream,
                       valbf, offsb, attnb, refp, midH);
    hipLaunchKernelGGL(gemm_out_kernel, dim3(GRIDX), dim3(512), 0, stream,
                       midH, packB, b_out, out);
}

// Round 12
// 79.867 us; speedup vs baseline: 1.3285x; 1.3285x over previous
//
#include <hip/hip_runtime.h>
#include <math.h>

#define B_    2
#define LQ_   12240
#define C_    256
#define NH_   8
#define NL_   4
#define NP_   4
#define LEN_IN_ 12240
#define MROWS (B_*LQ_)    // 24480
#define MF_   (MROWS/16)  // 1530
#define KF_   8           // 256/32
#define APLANE ((size_t)MROWS * C_)
#define NBLK  383          // ceil(MROWS/64)

typedef __attribute__((ext_vector_type(8))) short short8v;
typedef __attribute__((ext_vector_type(4))) float f32x4;
typedef __attribute__((ext_vector_type(2))) float f32x2;
typedef __attribute__((ext_vector_type(2))) uint  u32x2;

__device__ __forceinline__ ushort f2bf_hi(float f) {
    uint u = __builtin_bit_cast(uint, f);
    uint r = (u + 0x7fffu + ((u >> 16) & 1u)) >> 16;
    return (ushort)r;
}
__device__ __forceinline__ float bf2f(ushort h) {
    uint u = ((uint)h) << 16;
    return __builtin_bit_cast(float, u);
}

// packed-B layout (uint4 units):
#define U4_VAL  0
#define U4_OFF  8192
#define U4_ATT  16384
#define U4_UHI  20480
#define U4_ULO  28672
#define PACKB_TOTAL 294912   // ushorts

#define ESTRIDE 272          // bf16 epilogue LDS stride (16B-aligned, conflict-free)
#define FSTRIDE 268          // f32 epilogue LDS stride

// ---------------------------------------------------------------------------
// Weights-only pack: B-fragment order, hi (+lo for W_out).
// ---------------------------------------------------------------------------
__global__ __launch_bounds__(256) void pack_w_kernel(
    const float* __restrict__ Wv, const float* __restrict__ Wo,
    const float* __restrict__ Wa, const float* __restrict__ Wu,
    ushort* __restrict__ packB)
{
    int gid = blockIdx.x * 256 + threadIdx.x;
    if (gid >= 28672) return;
    const float* W; ushort* hi; ushort* lo = nullptr; int N, rel;
    if (gid < 8192)       { W = Wv; hi = packB;          N = 256; rel = gid; }
    else if (gid < 16384) { W = Wo; hi = packB + 65536;  N = 256; rel = gid - 8192; }
    else if (gid < 20480) { W = Wa; hi = packB + 131072; N = 128; rel = gid - 16384; }
    else { W = Wu; hi = packB + 163840; lo = packB + 229376; N = 256; rel = gid - 20480; }

    const int lane = rel & 63;
    const int kf   = (rel >> 6) & 7;
    const int nf   = rel >> 9;
    const int row0 = kf * 32 + (lane >> 4) * 8;
    const int col  = nf * 16 + (lane & 15);

    union { ushort u16[8]; uint4 u4; } ch, cl;
#pragma unroll
    for (int j = 0; j < 8; ++j) {
        float x = W[(size_t)(row0 + j) * N + col];
        ushort h = f2bf_hi(x);
        ch.u16[j] = h;
        cl.u16[j] = f2bf_hi(x - bf2f(h));
    }
    *reinterpret_cast<uint4*>(hi + (size_t)rel * 8) = ch.u4;
    if (lo) *reinterpret_cast<uint4*>(lo + (size_t)rel * 8) = cl.u4;
}

// ---------------------------------------------------------------------------
// Merged value+query GEMM (R9 structure + LDS-repack coalesced epilogues).
// grid (NBLK, 2): y==0 -> valbf(bf16); y==1 -> offsb(bf16) + attnb(bf16,softmaxed).
// 512 thr (8 waves), 64 rows/block; A f32->bf16-hi staged fragment-linear in
// Sh; B fragments streamed from L2.  Epilogue: results -> Sh (stride 272),
// then coalesced uint4 stores.
// ---------------------------------------------------------------------------
__global__ __launch_bounds__(512) void gemm_vq_kernel(
    const float* __restrict__ inflat, const float* __restrict__ query,
    const ushort* __restrict__ packB,
    const float* __restrict__ b_val, const float* __restrict__ b_off,
    const float* __restrict__ b_attn,
    ushort* __restrict__ valbf, ushort* __restrict__ offsb, ushort* __restrict__ attnb)
{
    const int t = threadIdx.x, lane = t & 63, wid = t >> 6;
    const int rowBase = blockIdx.x * 64;
    const bool isVal = (blockIdx.y == 0);
    const float* __restrict__ A = isVal ? inflat : query;

    __shared__ ushort Sh[64 * ESTRIDE];   // 34816 B; staging uses first 32 KB

    // ---- stage A tile (64 x 256) f32 -> bf16-hi, fragment-linear ----
#pragma unroll
    for (int i = 0; i < 4; ++i) {
        int frag = i * 512 + t;
        int fl = frag & 63, kf = (frag >> 6) & 7, mf = frag >> 9;
        int row = min(rowBase + mf * 16 + (fl & 15), MROWS - 1);
        int k0 = kf * 32 + (fl >> 4) * 8;
        const float4* s = reinterpret_cast<const float4*>(A + (size_t)row * 256 + k0);
        float4 v0 = s[0], v1 = s[1];
        float vv[8] = { v0.x, v0.y, v0.z, v0.w, v1.x, v1.y, v1.z, v1.w };
        union { ushort u16[8]; uint4 u4; } hh;
#pragma unroll
        for (int j = 0; j < 8; ++j) hh.u16[j] = f2bf_hi(vv[j]);
        *reinterpret_cast<uint4*>(&Sh[(size_t)frag * 8]) = hh.u4;
    }
    __syncthreads();

    const uint4* A4 = reinterpret_cast<const uint4*>(Sh);
    const int colLane = lane & 15, rquad = lane >> 4;
    const int wnf = wid * 2;

    if (isVal) {
        const uint4* B4 = reinterpret_cast<const uint4*>(packB) + U4_VAL;
        f32x4 acc[4][2];
#pragma unroll
        for (int mi = 0; mi < 4; ++mi)
#pragma unroll
            for (int f = 0; f < 2; ++f) acc[mi][f] = (f32x4)0.0f;

#pragma unroll
        for (int kf = 0; kf < KF_; ++kf) {
            uint4 bh[2], ah[4];
#pragma unroll
            for (int f = 0; f < 2; ++f) bh[f] = B4[((wnf + f) * KF_ + kf) * 64 + lane];
#pragma unroll
            for (int mi = 0; mi < 4; ++mi) ah[mi] = A4[(mi * KF_ + kf) * 64 + lane];
#pragma unroll
            for (int mi = 0; mi < 4; ++mi) {
                short8v a = __builtin_bit_cast(short8v, ah[mi]);
#pragma unroll
                for (int f = 0; f < 2; ++f)
                    acc[mi][f] = __builtin_amdgcn_mfma_f32_16x16x32_bf16(
                        a, __builtin_bit_cast(short8v, bh[f]), acc[mi][f], 0, 0, 0);
            }
        }
        __syncthreads();   // staging dead; reuse Sh for epilogue
#pragma unroll
        for (int f = 0; f < 2; ++f) {
            int col = (wnf + f) * 16 + colLane;
            float bv = b_val[col];
#pragma unroll
            for (int mi = 0; mi < 4; ++mi)
#pragma unroll
                for (int e = 0; e < 4; ++e)
                    Sh[(mi * 16 + rquad * 4 + e) * ESTRIDE + col] = f2bf_hi(acc[mi][f][e] + bv);
        }
        __syncthreads();
#pragma unroll
        for (int i = 0; i < 4; ++i) {
            int idx = i * 512 + t, row = idx >> 5, c8 = idx & 31;
            int grow = rowBase + row;
            if (grow < MROWS)
                *reinterpret_cast<uint4*>(valbf + (size_t)grow * 256 + c8 * 8) =
                    *reinterpret_cast<const uint4*>(&Sh[row * ESTRIDE + c8 * 8]);
        }
    } else {
        const uint4* BO = reinterpret_cast<const uint4*>(packB) + U4_OFF;
        const uint4* BA = reinterpret_cast<const uint4*>(packB) + U4_ATT;
        f32x4 acc[4][3];
#pragma unroll
        for (int mi = 0; mi < 4; ++mi)
#pragma unroll
            for (int f = 0; f < 3; ++f) acc[mi][f] = (f32x4)0.0f;

#pragma unroll
        for (int kf = 0; kf < KF_; ++kf) {
            uint4 bh[3], ah[4];
#pragma unroll
            for (int f = 0; f < 2; ++f) bh[f] = BO[((wnf + f) * KF_ + kf) * 64 + lane];
            bh[2] = BA[(wid * KF_ + kf) * 64 + lane];
#pragma unroll
            for (int mi = 0; mi < 4; ++mi) ah[mi] = A4[(mi * KF_ + kf) * 64 + lane];
#pragma unroll
            for (int mi = 0; mi < 4; ++mi) {
                short8v a = __builtin_bit_cast(short8v, ah[mi]);
#pragma unroll
                for (int f = 0; f < 3; ++f)
                    acc[mi][f] = __builtin_amdgcn_mfma_f32_16x16x32_bf16(
                        a, __builtin_bit_cast(short8v, bh[f]), acc[mi][f], 0, 0, 0);
            }
        }
        __syncthreads();
        // ---- offs epilogue (bf16, repacked) ----
#pragma unroll
        for (int f = 0; f < 2; ++f) {
            int col = (wnf + f) * 16 + colLane;
            float bv = b_off[col];
#pragma unroll
            for (int mi = 0; mi < 4; ++mi)
#pragma unroll
                for (int e = 0; e < 4; ++e)
                    Sh[(mi * 16 + rquad * 4 + e) * ESTRIDE + col] = f2bf_hi(acc[mi][f][e] + bv);
        }
        __syncthreads();
#pragma unroll
        for (int i = 0; i < 4; ++i) {
            int idx = i * 512 + t, row = idx >> 5, c8 = idx & 31;
            int grow = rowBase + row;
            if (grow < MROWS)
                *reinterpret_cast<uint4*>(offsb + (size_t)grow * 256 + c8 * 8) =
                    *reinterpret_cast<const uint4*>(&Sh[row * ESTRIDE + c8 * 8]);
        }
        __syncthreads();
        // ---- attn epilogue: softmax (16-lane groups) + bf16 repack ----
        {
            int col = wid * 16 + colLane;
            float bv = b_attn[col];
#pragma unroll
            for (int mi = 0; mi < 4; ++mi)
#pragma unroll
                for (int e = 0; e < 4; ++e) {
                    float v = acc[mi][2][e] + bv;
                    float mx = v;
#pragma unroll
                    for (int m = 8; m >= 1; m >>= 1) mx = fmaxf(mx, __shfl_xor(mx, m, 16));
                    float ex = __expf(v - mx);
                    float s = ex;
#pragma unroll
                    for (int m = 8; m >= 1; m >>= 1) s += __shfl_xor(s, m, 16);
                    Sh[(mi * 16 + rquad * 4 + e) * ESTRIDE + col] = f2bf_hi(ex / s);
                }
        }
        __syncthreads();
#pragma unroll
        for (int i = 0; i < 2; ++i) {
            int idx = i * 512 + t, row = idx >> 4, c8 = idx & 15;
            int grow = rowBase + row;
            if (grow < MROWS)
                *reinterpret_cast<uint4*>(attnb + (size_t)grow * 128 + c8 * 8) =
                    *reinterpret_cast<const uint4*>(&Sh[row * ESTRIDE + c8 * 8]);
        }
    }
}

// ---------------------------------------------------------------------------
// Out GEMM (R9 structure + f32 LDS-repack epilogue, 2 half-tile phases).
// ---------------------------------------------------------------------------
__global__ __launch_bounds__(512) void gemm_out_kernel(
    const ushort* __restrict__ midH, const ushort* __restrict__ packB,
    const float* __restrict__ bias, float* __restrict__ Cg)
{
    const int t = threadIdx.x, lane = t & 63, wid = t >> 6;
    const int rowBase = blockIdx.x * 64;

    __shared__ ushort Sh[64 * ESTRIDE];   // 34816 B (covers 32*268*4B epilogue)

    const uint4* H4 = reinterpret_cast<const uint4*>(midH);
#pragma unroll
    for (int i = 0; i < 4; ++i) {
        int frag = i * 512 + t;
        int fl = frag & 63, kf = (frag >> 6) & 7, mf = frag >> 9;
        int row = min(rowBase + mf * 16 + (fl & 15), MROWS - 1);
        int kq = kf * 4 + (fl >> 4);
        *reinterpret_cast<uint4*>(&Sh[(size_t)frag * 8]) = H4[(size_t)row * 32 + kq];
    }
    __syncthreads();

    const uint4* BH4 = reinterpret_cast<const uint4*>(packB) + U4_UHI;
    const uint4* BL4 = reinterpret_cast<const uint4*>(packB) + U4_ULO;
    const uint4* A4 = reinterpret_cast<const uint4*>(Sh);
    const int wnf = wid * 2;

    f32x4 acc[4][2];
#pragma unroll
    for (int mi = 0; mi < 4; ++mi)
#pragma unroll
        for (int f = 0; f < 2; ++f) acc[mi][f] = (f32x4)0.0f;

#pragma unroll
    for (int kf = 0; kf < KF_; ++kf) {
        uint4 bh[2], bl[2], ah[4];
#pragma unroll
        for (int f = 0; f < 2; ++f) {
            bh[f] = BH4[((wnf + f) * KF_ + kf) * 64 + lane];
            bl[f] = BL4[((wnf + f) * KF_ + kf) * 64 + lane];
        }
#pragma unroll
        for (int mi = 0; mi < 4; ++mi) ah[mi] = A4[(mi * KF_ + kf) * 64 + lane];
#pragma unroll
        for (int mi = 0; mi < 4; ++mi) {
            short8v a = __builtin_bit_cast(short8v, ah[mi]);
#pragma unroll
            for (int f = 0; f < 2; ++f) {
                acc[mi][f] = __builtin_amdgcn_mfma_f32_16x16x32_bf16(
                    a, __builtin_bit_cast(short8v, bh[f]), acc[mi][f], 0, 0, 0);
                acc[mi][f] = __builtin_amdgcn_mfma_f32_16x16x32_bf16(
                    a, __builtin_bit_cast(short8v, bl[f]), acc[mi][f], 0, 0, 0);
            }
        }
    }

    const int colLane = lane & 15, rquad = lane >> 4;
    float* ShF = reinterpret_cast<float*>(Sh);
#pragma unroll
    for (int phase = 0; phase < 2; ++phase) {
        __syncthreads();
#pragma unroll
        for (int f = 0; f < 2; ++f) {
            int col = (wnf + f) * 16 + colLane;
            float bv = bias[col];
#pragma unroll
            for (int mi2 = 0; mi2 < 2; ++mi2) {
                int mi = phase * 2 + mi2;
#pragma unroll
                for (int e = 0; e < 4; ++e)
                    ShF[(mi2 * 16 + rquad * 4 + e) * FSTRIDE + col] = acc[mi][f][e] + bv;
            }
        }
        __syncthreads();
#pragma unroll
        for (int i = 0; i < 4; ++i) {
            int idx = i * 512 + t, row = idx >> 6, c4 = idx & 63;
            int grow = rowBase + phase * 32 + row;
            if (grow < MROWS)
                *reinterpret_cast<float4*>(Cg + (size_t)grow * 256 + c4 * 4) =
                    *reinterpret_cast<const float4*>(&ShF[row * FSTRIDE + c4 * 4]);
        }
    }
}

// ---------------------------------------------------------------------------
// Sampler: bf16 offs/attn inputs (softmax pre-applied); packed f32 FMA +
// free-hi bf16 decode; writes midH (bf16, coalesced).
// ---------------------------------------------------------------------------
__global__ __launch_bounds__(128) void sampler_kernel(
    const ushort* __restrict__ value,
    const ushort* __restrict__ offs,    // bf16 (B*LQ, 256)
    const ushort* __restrict__ attnw,   // bf16 softmaxed (B*LQ, 128)
    const float* __restrict__ refp,
    ushort* __restrict__ midH)
{
    const int t  = threadIdx.x;
    const int qi = t >> 6;
    const int t6 = t & 63;
    const int q  = blockIdx.x * 2 + qi;

    __shared__ float s_ref[2][8];
    __shared__ int   s_addr[2][576];
    __shared__ float s_w[2][576];

    if (t < 16) s_ref[t >> 3][t & 7] = refp[(size_t)(blockIdx.x * 2 + (t >> 3)) * 8 + (t & 7)];
    __syncthreads();

#pragma unroll
    for (int batch = 0; batch < 2; ++batch) {
        const int p  = t6 + batch * 64;
        const int h  = p >> 4;
        const int lp = p & 15;
        const int l  = lp >> 2;

        const float aw = bf2f(attnw[(size_t)q * 128 + p]);
        const uint o2 = reinterpret_cast<const uint*>(offs)[(size_t)q * 128 + p];
        const float ox = bf2f((ushort)(o2 & 0xffffu));
        const float oy = bf2f((ushort)(o2 >> 16));
        const float rx = s_ref[qi][l * 2 + 0];
        const float ry = s_ref[qi][l * 2 + 1];

        const int   Wl = 96 >> l;
        const int   st = 12288 - (12288 >> (2 * l));
        const float fW = (float)Wl;

        const float x = fmaf(rx, fW, ox) - 0.5f;
        const float y = fmaf(ry, fW, oy) - 0.5f;
        const float x0f = floorf(x), y0f = floorf(y);
        const float fx = x - x0f, fy = y - y0f;
        const int x0 = (int)x0f, y0 = (int)y0f;
        const int x1 = x0 + 1,   y1 = y0 + 1;

        const float vx0 = (x0 >= 0 && x0 < Wl) ? 1.f : 0.f;
        const float vx1 = (x1 >= 0 && x1 < Wl) ? 1.f : 0.f;
        const float vy0 = (y0 >= 0 && y0 < Wl) ? 1.f : 0.f;
        const float vy1 = (y1 >= 0 && y1 < Wl) ? 1.f : 0.f;

        const int xc0 = min(max(x0, 0), Wl - 1);
        const int xc1 = min(max(x1, 0), Wl - 1);
        const int yc0 = min(max(y0, 0), Wl - 1);
        const int yc1 = min(max(y1, 0), Wl - 1);

        const int row0 = st + yc0 * Wl;
        const int row1 = st + yc1 * Wl;
        const int hb   = h << 5;

        const int sidx = (lp * 9 + h) * 4;
        int4 a;
        a.x = ((row0 + xc0) << 8) + hb;
        a.y = ((row0 + xc1) << 8) + hb;
        a.z = ((row1 + xc0) << 8) + hb;
        a.w = ((row1 + xc1) << 8) + hb;
        *reinterpret_cast<int4*>(&s_addr[qi][sidx]) = a;

        float4 w;
        w.x = aw * (1.f - fx) * (1.f - fy) * vx0 * vy0;
        w.y = aw * fx * (1.f - fy) * vx1 * vy0;
        w.z = aw * (1.f - fx) * fy * vx0 * vy1;
        w.w = aw * fx * fy * vx1 * vy1;
        *reinterpret_cast<float4*>(&s_w[qi][sidx]) = w;
    }
    __syncthreads();

    const int c2 = t6 >> 5;
    const int h  = (t6 >> 2) & 7;
    const int l2 = t6 & 3;
    const int d8 = l2 * 8;
    const ushort* __restrict__ vb = value + (q >= LQ_ ? (size_t)LEN_IN_ * 256 : 0) + d8;

    f32x2 aLo = (f32x2)0.f, aHi = (f32x2)0.f, bLo = (f32x2)0.f, bHi = (f32x2)0.f;

#pragma unroll
    for (int pt = 0; pt < 16; ++pt) {
        const int base = (pt * 9 + h) * 4 + c2 * 2;
        const int2   a = *reinterpret_cast<const int2*>(&s_addr[qi][base]);
        const float2 w = *reinterpret_cast<const float2*>(&s_w[qi][base]);
        uint4 v0 = *reinterpret_cast<const uint4*>(vb + a.x);
        uint4 v1 = *reinterpret_cast<const uint4*>(vb + a.y);
        f32x2 w0; w0.x = w.x; w0.y = w.x;
        f32x2 w1; w1.x = w.y; w1.y = w.y;

        u32x2 h01; h01.x = v0.x; h01.y = v0.y;
        u32x2 h23; h23.x = v0.z; h23.y = v0.w;
        u32x2 l01 = h01 << 16, l23 = h23 << 16;
        aHi = __builtin_elementwise_fma(__builtin_bit_cast(f32x2, h01), w0, aHi);
        aLo = __builtin_elementwise_fma(__builtin_bit_cast(f32x2, l01), w0, aLo);
        bHi = __builtin_elementwise_fma(__builtin_bit_cast(f32x2, h23), w0, bHi);
        bLo = __builtin_elementwise_fma(__builtin_bit_cast(f32x2, l23), w0, bLo);

        u32x2 g01; g01.x = v1.x; g01.y = v1.y;
        u32x2 g23; g23.x = v1.z; g23.y = v1.w;
        u32x2 m01 = g01 << 16, m23 = g23 << 16;
        aHi = __builtin_elementwise_fma(__builtin_bit_cast(f32x2, g01), w1, aHi);
        aLo = __builtin_elementwise_fma(__builtin_bit_cast(f32x2, m01), w1, aLo);
        bHi = __builtin_elementwise_fma(__builtin_bit_cast(f32x2, g23), w1, bHi);
        bLo = __builtin_elementwise_fma(__builtin_bit_cast(f32x2, m23), w1, bLo);
    }

    float r[8] = { aLo.x, aHi.x, aLo.y, aHi.y, bLo.x, bHi.x, bLo.y, bHi.y };
#pragma unroll
    for (int j = 0; j < 8; ++j) r[j] += __shfl_xor(r[j], 32);

    if (c2 == 0) {
        union { ushort u16[8]; uint4 u4; } hh;
#pragma unroll
        for (int j = 0; j < 8; ++j) hh.u16[j] = f2bf_hi(r[j]);
        *reinterpret_cast<uint4*>(midH + (size_t)q * 256 + (h << 5) + d8) = hh.u4;
    }
}

// ---------------------------------------------------------------------------
extern "C" void kernel_launch(void* const* d_in, const int* in_sizes, int n_in,
                              void* d_out, int out_size, void* d_ws, size_t ws_size,
                              hipStream_t stream)
{
    const float* query  = (const float*)d_in[0];
    const float* refp   = (const float*)d_in[1];
    const float* inflat = (const float*)d_in[2];
    const float* W_off  = (const float*)d_in[5];
    const float* b_off  = (const float*)d_in[6];
    const float* W_attn = (const float*)d_in[7];
    const float* b_attn = (const float*)d_in[8];
    const float* W_val  = (const float*)d_in[9];
    const float* b_val  = (const float*)d_in[10];
    const float* W_out  = (const float*)d_in[11];
    const float* b_out  = (const float*)d_in[12];
    float* out = (float*)d_out;

    ushort* midH  = (ushort*)d_ws;
    ushort* valbf = midH + APLANE;
    ushort* packB = valbf + APLANE;
    ushort* offsb = packB + PACKB_TOTAL;            // bf16 (B*LQ, 256)
    ushort* attnb = offsb + APLANE;                 // bf16 (B*LQ, 128)

    hipLaunchKernelGGL(pack_w_kernel, dim3(112), dim3(256), 0, stream,
                       W_val, W_off, W_attn, W_out, packB);
    hipLaunchKernelGGL(gemm_vq_kernel, dim3(NBLK, 2), dim3(512), 0, stream,
                       inflat, query, packB, b_val, b_off, b_attn,
                       valbf, offsb, attnb);
    hipLaunchKernelGGL(sampler_kernel, dim3(MROWS / 2), dim3(128), 0, stream,
                       valbf, offsb, attnb, refp, midH);
    hipLaunchKernelGGL(gemm_out_kernel, dim3(NBLK), dim3(512), 0, stream,
                       midH, packB, b_out, out);
}